// Round 7
// baseline (501.831 us; speedup 1.0000x reference)
//
#include <hip/hip_runtime.h>
#include <hip/hip_cooperative_groups.h>

namespace cg = cooperative_groups;

#define NG    64
#define NPG   128
#define KNN   100
#define FIN   6
#define WID   128
#define D2    768
#define NEG   0.01f
#define INV101 (1.0f/101.0f)
#define BNEPS 1e-5f
#define BIG   1e30f

__device__ __forceinline__ float leaky(float v) { return v > 0.f ? v : NEG * v; }

// monotone float -> uint mapping (a<b as float  <=>  ford(a)<ford(b) as uint)
__device__ __forceinline__ unsigned ford(float f) {
    unsigned u = __float_as_uint(f);
    return (u >> 31) ? ~u : (u | 0x80000000u);
}

// One cooperative kernel: grid 256 blocks x 256 threads, 1 block/CU.
// Block b: graph g = b&63, row-slab i0 = (b>>6)*32. (g=b&63 keeps a graph's
// 4 slabs on one XCD: (b+64)%8 == b%8.)
__global__ __launch_bounds__(256, 1) void k_mega(
    const float* __restrict__ x,
    const float* __restrict__ W1, const float* __restrict__ b1,
    const float* __restrict__ Wc, const float* __restrict__ bc,
    const float* __restrict__ bng, const float* __restrict__ bnb,
    const float* __restrict__ linW, const float* __restrict__ linb,
    const float* __restrict__ outW, const float* __restrict__ outb,
    float* __restrict__ A, float* __restrict__ H1, float* __restrict__ H2,
    float* __restrict__ WT,
    float* __restrict__ Zp, float* __restrict__ Zp3,
    float* __restrict__ ZT0, float* __restrict__ ZT1, float* __restrict__ out)
{
    cg::grid_group grid = cg::this_grid();
    const int b    = blockIdx.x;
    const int g    = b & 63;
    const int slab = b >> 6;
    const int i0   = slab * 32;
    const int t    = threadIdx.x;

    __shared__ float xg[NPG * FIN];      // persists ph0 -> ph1
    __shared__ float sq[NPG];
    __shared__ float A2s[32 * 132];      // persists ph1 -> convs (16.9 KB)
    __shared__ float Ps[4224];           // P slab [32][132] / transpose tile [64][65] / outW
    __shared__ float Bs[NPG * NPG];      // D slab / A full / h full / W panel (64 KB)
    __shared__ float p2[32 * FIN];
    __shared__ float W1s[FIN * WID];
    __shared__ float b1s[WID];
    __shared__ float red[4 * 64];

    // ================= Phase 0: kNN -> A = (I+M)/101 =================
    {
        const float* xp = x + g * NPG * FIN;
        for (int e = t; e < NPG * FIN; e += 256) xg[e] = xp[e];
        __syncthreads();
        if (t < NPG) {
            float s = 0.f;
            #pragma unroll
            for (int c = 0; c < FIN; ++c) { float v = xg[t * FIN + c]; s = fmaf(v, v, s); }
            sq[t] = s;
        }
        __syncthreads();
        for (int e = t; e < 32 * NPG; e += 256) {
            int il = e >> 7, j = e & 127;
            int i = i0 + il;
            float d;
            if (j == i) d = BIG;
            else {
                float dot = 0.f;
                #pragma unroll
                for (int c = 0; c < FIN; ++c) dot = fmaf(xg[i * FIN + c], xg[j * FIN + c], dot);
                d = sq[i] + sq[j] - 2.f * dot;
            }
            Bs[il * 128 + j] = d;
        }
        __syncthreads();
        // rank-select: thread -> (row il, 16 cols), lex keys ((ford(d)<<32)|j)
        int il = t >> 3, j0 = (t & 7) * 16;
        const float* Drow = &Bs[il * 128];
        unsigned long long jk[16];
        int cnt[16];
        #pragma unroll
        for (int u = 0; u < 16; ++u) {
            jk[u] = ((unsigned long long)ford(Drow[j0 + u]) << 32) | (unsigned)(j0 + u);
            cnt[u] = 0;
        }
        for (int k = 0; k < 128; ++k) {
            unsigned long long kk = ((unsigned long long)ford(Drow[k]) << 32) | (unsigned)k;
            #pragma unroll
            for (int u = 0; u < 16; ++u) cnt[u] += (kk < jk[u]) ? 1 : 0;
        }
        int i = i0 + il;
        float av[16];
        #pragma unroll
        for (int u = 0; u < 16; ++u)
            av[u] = (cnt[u] < KNN || (j0 + u) == i) ? INV101 : 0.f;
        float* Ag = A + (size_t)g * NPG * NPG + (size_t)i * NPG + j0;
        #pragma unroll
        for (int q = 0; q < 4; ++q)
            *(float4*)&Ag[q * 4] = make_float4(av[q*4], av[q*4+1], av[q*4+2], av[q*4+3]);
    }
    grid.sync();   // S1

    // ============ Phase 1: A2 slab = (A@A)[i0:i0+32,:] (kept in LDS) + conv1 ============
    {
        const float* Ag = A + (size_t)g * NPG * NPG;
        for (int t4 = t; t4 < NPG * NPG / 4; t4 += 256)
            *(float4*)&Bs[t4 * 4] = *(const float4*)&Ag[t4 * 4];
        for (int e = t; e < FIN * WID; e += 256) W1s[e] = W1[e];
        if (t < WID) b1s[t] = b1[t];
        __syncthreads();
        int ty = t >> 4, tx = t & 15;
        int r0 = ty * 2, cj = tx * 8;
        float acc[2][8] = {};
        for (int k = 0; k < NPG; ++k) {
            float a0 = Bs[(i0 + r0) * 128 + k];
            float a1 = Bs[(i0 + r0 + 1) * 128 + k];
            float4 q0 = *(const float4*)&Bs[k * 128 + cj];
            float4 q1 = *(const float4*)&Bs[k * 128 + cj + 4];
            float bb[8] = {q0.x, q0.y, q0.z, q0.w, q1.x, q1.y, q1.z, q1.w};
            #pragma unroll
            for (int c = 0; c < 8; ++c) {
                acc[0][c] = fmaf(a0, bb[c], acc[0][c]);
                acc[1][c] = fmaf(a1, bb[c], acc[1][c]);
            }
        }
        #pragma unroll
        for (int r = 0; r < 2; ++r) {
            *(float4*)&A2s[(r0 + r) * 132 + cj]     = make_float4(acc[r][0], acc[r][1], acc[r][2], acc[r][3]);
            *(float4*)&A2s[(r0 + r) * 132 + cj + 4] = make_float4(acc[r][4], acc[r][5], acc[r][6], acc[r][7]);
        }
        __syncthreads();
        if (t < 32 * FIN) {
            int i = t / FIN, d = t - i * FIN;
            float s = 0.f;
            for (int k = 0; k < NPG; ++k) s = fmaf(A2s[i * 132 + k], xg[k * FIN + d], s);
            p2[t] = s;
        }
        __syncthreads();
        for (int e = t; e < 32 * WID; e += 256) {
            int i = e >> 7, o = e & 127;
            float s = b1s[o];
            #pragma unroll
            for (int d = 0; d < FIN; ++d) s = fmaf(p2[i * FIN + d], W1s[d * WID + o], s);
            H1[(size_t)(g * NPG + i0 + i) * WID + o] = leaky(s);
        }
    }
    grid.sync();   // S2

    // ============ Phases 2-3: conv2 (h1->h2, pool h1), conv3 (h2->pool3, pool h2) ============
    for (int f = 0; f < 2; ++f) {
        const float* Hin  = f ? H2 : H1;
        const float* W    = Wc + f * WID * WID;
        const float* bias = bc + f * WID;
        const float* hg = Hin + (size_t)g * NPG * WID;
        for (int t4 = t; t4 < NPG * WID / 4; t4 += 256)
            *(float4*)&Bs[t4 * 4] = *(const float4*)&hg[t4 * 4];
        __syncthreads();
        // full pool of the staged INPUT h -> Zp columns [f*256, f*256+256)
        if (slab == 0 && t < WID) {
            float sm = 0.f, mx = -BIG;
            for (int i = 0; i < NPG; ++i) { float v = Bs[i * WID + t]; sm += v; mx = fmaxf(mx, v); }
            Zp[g * D2 + f * 256 + t]       = sm * (1.f / NPG);
            Zp[g * D2 + f * 256 + WID + t] = mx;
        }
        int ty = t >> 4, tx = t & 15;
        int r0 = ty * 2, cj = tx * 8;
        {   // P slab = A2_slab @ h   -> Ps[32][132]
            float acc[2][8] = {};
            for (int k = 0; k < NPG; ++k) {
                float a0 = A2s[r0 * 132 + k];
                float a1 = A2s[(r0 + 1) * 132 + k];
                float4 q0 = *(const float4*)&Bs[k * WID + cj];
                float4 q1 = *(const float4*)&Bs[k * WID + cj + 4];
                float bb[8] = {q0.x, q0.y, q0.z, q0.w, q1.x, q1.y, q1.z, q1.w};
                #pragma unroll
                for (int c = 0; c < 8; ++c) {
                    acc[0][c] = fmaf(a0, bb[c], acc[0][c]);
                    acc[1][c] = fmaf(a1, bb[c], acc[1][c]);
                }
            }
            #pragma unroll
            for (int r = 0; r < 2; ++r) {
                *(float4*)&Ps[(r0 + r) * 132 + cj]     = make_float4(acc[r][0], acc[r][1], acc[r][2], acc[r][3]);
                *(float4*)&Ps[(r0 + r) * 132 + cj + 4] = make_float4(acc[r][4], acc[r][5], acc[r][6], acc[r][7]);
            }
            __syncthreads();
        }
        float o2[2][8];
        {   // h' = leaky(P @ W + b)
            float acc[2][8] = {};
            for (int d = 0; d < NPG; ++d) {
                float a0 = Ps[r0 * 132 + d];
                float a1 = Ps[(r0 + 1) * 132 + d];
                float4 w0 = *(const float4*)&W[d * WID + cj];
                float4 w1 = *(const float4*)&W[d * WID + cj + 4];
                float bb[8] = {w0.x, w0.y, w0.z, w0.w, w1.x, w1.y, w1.z, w1.w};
                #pragma unroll
                for (int c = 0; c < 8; ++c) {
                    acc[0][c] = fmaf(a0, bb[c], acc[0][c]);
                    acc[1][c] = fmaf(a1, bb[c], acc[1][c]);
                }
            }
            #pragma unroll
            for (int r = 0; r < 2; ++r)
                #pragma unroll
                for (int c = 0; c < 8; ++c)
                    o2[r][c] = leaky(acc[r][c] + bias[cj + c]);
        }
        if (f == 0) {
            #pragma unroll
            for (int r = 0; r < 2; ++r) {
                *(float4*)&H2[(size_t)(g * NPG + i0 + r0 + r) * WID + cj]     = make_float4(o2[r][0], o2[r][1], o2[r][2], o2[r][3]);
                *(float4*)&H2[(size_t)(g * NPG + i0 + r0 + r) * WID + cj + 4] = make_float4(o2[r][4], o2[r][5], o2[r][6], o2[r][7]);
            }
        } else {
            __syncthreads();   // all reads of Ps (P slab) done -> overwrite with h3 slab
            #pragma unroll
            for (int r = 0; r < 2; ++r) {
                *(float4*)&Ps[(r0 + r) * 132 + cj]     = make_float4(o2[r][0], o2[r][1], o2[r][2], o2[r][3]);
                *(float4*)&Ps[(r0 + r) * 132 + cj + 4] = make_float4(o2[r][4], o2[r][5], o2[r][6], o2[r][7]);
            }
            __syncthreads();
            // partial pool of this 32-row h3 slab -> Zp3[(g*4+slab)][{sum,max}][128]
            if (t < WID) {
                float sm = 0.f, mx = -BIG;
                for (int i = 0; i < 32; ++i) { float v = Ps[i * 132 + t]; sm += v; mx = fmaxf(mx, v); }
                Zp3[(size_t)(g * 4 + slab) * 256 + t]       = sm;
                Zp3[(size_t)(g * 4 + slab) * 256 + 128 + t] = mx;
            }
        }
        grid.sync();   // S3, S4
    }

    // ============ Phase 4: BN (blocks 0-2) + lin_W transpose (blocks 16-255) ============
    if (b < 3) {
        int c = b * 256 + t;
        float s = 0.f, s2 = 0.f;
        for (int r = 0; r < NG; ++r) {
            float v;
            if (c < 512) v = Zp[r * D2 + c];
            else if (c < 640) {
                int o = c - 512;
                float sm = 0.f;
                #pragma unroll
                for (int q = 0; q < 4; ++q) sm += Zp3[(size_t)(r * 4 + q) * 256 + o];
                v = sm * (1.f / NPG);
            } else {
                int o = c - 640;
                float mx = -BIG;
                #pragma unroll
                for (int q = 0; q < 4; ++q) mx = fmaxf(mx, Zp3[(size_t)(r * 4 + q) * 256 + 128 + o]);
                v = mx;
            }
            s += v; s2 = fmaf(v, v, s2);
        }
        float m   = s * (1.f / NG);
        float var = s2 * (1.f / NG) - m * m;
        float sc  = rsqrtf(var + BNEPS) * bng[c];
        float bt  = bnb[c];
        for (int r = 0; r < NG; ++r) {
            float v;
            if (c < 512) v = Zp[r * D2 + c];
            else if (c < 640) {
                int o = c - 512;
                float sm = 0.f;
                #pragma unroll
                for (int q = 0; q < 4; ++q) sm += Zp3[(size_t)(r * 4 + q) * 256 + o];
                v = sm * (1.f / NPG);
            } else {
                int o = c - 640;
                float mx = -BIG;
                #pragma unroll
                for (int q = 0; q < 4; ++q) mx = fmaxf(mx, Zp3[(size_t)(r * 4 + q) * 256 + 128 + o]);
                v = mx;
            }
            ZT0[c * NG + r] = (v - m) * sc + bt;
        }
    } else if (b >= 16) {
        // transpose lin_W (5 x 768 x 768) into WT[l][col][k]; 720 tiles of 64x64, 3 per block
        for (int tile = (b - 16) * 3; tile < (b - 16) * 3 + 3; ++tile) {
            int l = tile / 144, rem = tile % 144;
            int trow = rem / 12, tcol = rem % 12;
            const float* Wl = linW + (size_t)l * D2 * D2;
            int r = t >> 4, c4 = (t & 15) * 4;
            #pragma unroll
            for (int j = 0; j < 4; ++j) {
                float4 v = *(const float4*)&Wl[(size_t)(trow * 64 + r + j * 16) * D2 + tcol * 64 + c4];
                Ps[(r + j * 16) * 65 + c4 + 0] = v.x;
                Ps[(r + j * 16) * 65 + c4 + 1] = v.y;
                Ps[(r + j * 16) * 65 + c4 + 2] = v.z;
                Ps[(r + j * 16) * 65 + c4 + 3] = v.w;
            }
            __syncthreads();
            int oc = t >> 4, r4 = (t & 15) * 4;
            #pragma unroll
            for (int j = 0; j < 4; ++j) {
                int c = oc + j * 16;
                float4 v = {Ps[(r4 + 0) * 65 + c], Ps[(r4 + 1) * 65 + c],
                            Ps[(r4 + 2) * 65 + c], Ps[(r4 + 3) * 65 + c]};
                *(float4*)&WT[(size_t)l * D2 * D2 + (size_t)(tcol * 64 + c) * D2 + trow * 64 + r4] = v;
            }
            __syncthreads();
        }
    }
    grid.sync();   // S5

    // ============ Phases 5-9: MLP layers. 96 blocks x 8 cols; WT panel in LDS (coalesced, once) ============
    for (int l = 0; l < 5; ++l) {
        const float* zin  = (l & 1) ? ZT1 : ZT0;
        float*       zout = (l & 1) ? ZT0 : ZT1;
        if (b < 96) {
            const int c0 = b * 8;
            const float* WTp = WT + (size_t)l * D2 * D2 + (size_t)c0 * D2;
            for (int u4 = t; u4 < (8 * D2) / 4; u4 += 256)
                *(float4*)&Bs[u4 * 4] = *(const float4*)&WTp[u4 * 4];
            __syncthreads();
            const int w = t >> 6, r = t & 63;
            const int cA = c0 + 2 * w, cB = cA + 1;
            const float* wArow = &Bs[(2 * w) * D2];
            const float* wBrow = &Bs[(2 * w + 1) * D2];
            const float* zp = zin + r;
            float sA = 0.f, sB = 0.f;
            #pragma unroll 4
            for (int k4 = 0; k4 < D2 / 4; ++k4) {
                float4 wa = *(const float4*)&wArow[k4 * 4];
                float4 wb = *(const float4*)&wBrow[k4 * 4];
                float z0 = zp[(k4 * 4 + 0) * NG];
                float z1 = zp[(k4 * 4 + 1) * NG];
                float z2 = zp[(k4 * 4 + 2) * NG];
                float z3 = zp[(k4 * 4 + 3) * NG];
                sA = fmaf(z0, wa.x, sA); sB = fmaf(z0, wb.x, sB);
                sA = fmaf(z1, wa.y, sA); sB = fmaf(z1, wb.y, sB);
                sA = fmaf(z2, wa.z, sA); sB = fmaf(z2, wb.z, sB);
                sA = fmaf(z3, wa.w, sA); sB = fmaf(z3, wb.w, sB);
            }
            zout[cA * NG + r] = leaky(sA + linb[l * D2 + cA]);
            zout[cB * NG + r] = leaky(sB + linb[l * D2 + cB]);
            __syncthreads();   // Bs reloaded next layer
        }
        grid.sync();   // S6..S10
    }

    // ============ Phase 10: output head ============
    if (b == 0) {
        const float* zin = ZT1;   // after 5 layers
        for (int u = t; u < D2; u += 256) Ps[u] = outW[u];
        __syncthreads();
        int row = t & 63, kq = t >> 6;
        const float* zp = zin + kq * 192 * NG + row;
        float s = 0.f;
        #pragma unroll 8
        for (int k = 0; k < 192; ++k) s = fmaf(zp[k * NG], Ps[kq * 192 + k], s);
        red[kq * 64 + row] = s;
        __syncthreads();
        if (t < 64)
            out[t] = red[t] + red[64 + t] + red[128 + t] + red[192 + t] + outb[0];
    }
}

extern "C" void kernel_launch(void* const* d_in, const int* in_sizes, int n_in,
                              void* d_out, int out_size, void* d_ws, size_t ws_size,
                              hipStream_t stream)
{
    (void)in_sizes; (void)n_in; (void)out_size; (void)ws_size;
    const float* x       = (const float*)d_in[0];
    // d_in[1] = batch: fixed structure (i/128), unused
    const float* conv1_W = (const float*)d_in[2];
    const float* conv1_b = (const float*)d_in[3];
    const float* convs_W = (const float*)d_in[4];
    const float* convs_b = (const float*)d_in[5];
    const float* bn_g    = (const float*)d_in[6];
    const float* bn_b    = (const float*)d_in[7];
    const float* lin_W   = (const float*)d_in[8];
    const float* lin_b   = (const float*)d_in[9];
    const float* out_W   = (const float*)d_in[10];
    const float* out_b   = (const float*)d_in[11];

    float* A   = (float*)d_ws;           // 1M floats (dead after phase 1)
    float* H1  = A   + (1 << 20);        // 1M (dead after phase 2)
    float* H2  = H1  + (1 << 20);        // 1M (dead after phase 3)
    float* WT  = (float*)d_ws;           // 2.95M floats, aliases A/H1/H2 (written phase 4)
    float* Zp  = H2  + (1 << 20);        // offset 3M floats = 12 MB
    float* Zp3 = Zp  + NG * D2;
    float* ZT0 = Zp3 + NG * 4 * 256;
    float* ZT1 = ZT0 + NG * D2;
    float* outp = (float*)d_out;

    void* args[] = {
        (void*)&x, (void*)&conv1_W, (void*)&conv1_b, (void*)&convs_W, (void*)&convs_b,
        (void*)&bn_g, (void*)&bn_b, (void*)&lin_W, (void*)&lin_b,
        (void*)&out_W, (void*)&out_b,
        (void*)&A, (void*)&H1, (void*)&H2, (void*)&WT, (void*)&Zp, (void*)&Zp3,
        (void*)&ZT0, (void*)&ZT1, (void*)&outp
    };
    hipLaunchCooperativeKernel((void*)k_mega, dim3(256), dim3(256), args, 0, stream);
}

// Round 9
// 241.436 us; speedup vs baseline: 2.0785x; 2.0785x over previous
//
#include <hip/hip_runtime.h>

#define NG    64
#define NPG   128
#define KNN   100
#define FIN   6
#define WID   128
#define D2    768
#define NEG   0.01f
#define INV101 (1.0f/101.0f)
#define BNEPS 1e-5f
#define BIG   1e30f

#define AGENT __HIP_MEMORY_SCOPE_AGENT

__device__ __forceinline__ float leaky(float v) { return v > 0.f ? v : NEG * v; }

// barrier among `target` blocks on counter c (counter must be 0 before first use)
__device__ __forceinline__ void gbar(unsigned* c, unsigned target) {
    __syncthreads();
    if (threadIdx.x == 0) {
        __hip_atomic_fetch_add(c, 1u, __ATOMIC_ACQ_REL, AGENT);
        while (__hip_atomic_load(c, __ATOMIC_ACQUIRE, AGENT) < target)
            __builtin_amdgcn_s_sleep(2);
    }
    __syncthreads();
}

// ---------------- K1: kNN (rank-select) + A = (I+M)/101  [proven round-4 code] ----------------
// grid 512 (8 blocks/graph, 16 rows each), block 256
__global__ __launch_bounds__(256) void k_knn(const float* __restrict__ x, float* __restrict__ A)
{
    int g  = blockIdx.x >> 3;
    int i0 = (blockIdx.x & 7) * 16;
    __shared__ float xg[NPG * FIN];
    __shared__ float sq[NPG];
    __shared__ float D[16][NPG];
    const float* xp = x + g * NPG * FIN;
    for (int t = threadIdx.x; t < NPG * FIN; t += 256) xg[t] = xp[t];
    __syncthreads();
    if (threadIdx.x < NPG) {
        float s = 0.f;
        #pragma unroll
        for (int c = 0; c < FIN; ++c) { float v = xg[threadIdx.x * FIN + c]; s = fmaf(v, v, s); }
        sq[threadIdx.x] = s;
    }
    __syncthreads();
    for (int e = threadIdx.x; e < 16 * NPG; e += 256) {
        int il = e >> 7, j = e & 127;
        int i = i0 + il;
        float d;
        if (j == i) d = BIG;
        else {
            float dot = 0.f;
            #pragma unroll
            for (int c = 0; c < FIN; ++c) dot = fmaf(xg[i * FIN + c], xg[j * FIN + c], dot);
            d = sq[i] + sq[j] - 2.f * dot;
        }
        D[il][j] = d;
    }
    __syncthreads();
    float* Ag = A + (size_t)g * NPG * NPG;
    for (int e = threadIdx.x; e < 16 * NPG; e += 256) {
        int il = e >> 7, j = e & 127;
        int i = i0 + il;
        float aval;
        if (i == j) aval = INV101;
        else {
            float dj = D[il][j];
            int cnt = 0;
            #pragma unroll 8
            for (int k = 0; k < NPG; ++k) {
                float dk = D[il][k];
                cnt += (dk < dj || (dk == dj && k < j)) ? 1 : 0;
            }
            aval = (cnt < KNN) ? INV101 : 0.f;
        }
        Ag[i * NPG + j] = aval;
    }
}

// ---------------- K2: per-graph pipeline: A^2 -> conv1..conv3 + pools ----------------
// grid 128 (2 blocks/graph: half = b>>6 owns rows half*64..+64), block 256.
__global__ __launch_bounds__(256, 1) void k_graph(
    const float* __restrict__ A, const float* __restrict__ x,
    const float* __restrict__ W1, const float* __restrict__ b1,
    const float* __restrict__ Wc, const float* __restrict__ bc,
    float* __restrict__ Xp2, float* __restrict__ Xh2,
    float* __restrict__ Zp, float* __restrict__ Zp3, unsigned* __restrict__ cnt)
{
    const int b = blockIdx.x, g = b & 63, half = b >> 6;
    const int i0 = half * 64, i0p = 64 - i0;
    const int t = threadIdx.x;

    __shared__ float Bs[NPG * 132];      // A_full -> h1_full -> h2_full (67.6 KB)
    __shared__ float A2s[64 * 132];      // own A2 rows (33.8 KB)
    __shared__ float Ps[64 * 132];       // P_own / h3_own (33.8 KB)
    __shared__ float xg[NPG * FIN];
    __shared__ float p2f[NPG * 8];
    __shared__ float W1s[FIN * WID];
    __shared__ float b1s[WID];

    // ---- stage A_full, x, W1, b1 ----
    {
        const float* Ag = A + (size_t)g * NPG * NPG;
        for (int e4 = t; e4 < 4096; e4 += 256) {
            int r = e4 >> 5, c4 = (e4 & 31) * 4;
            *(float4*)&Bs[r * 132 + c4] = *(const float4*)&Ag[r * NPG + c4];
        }
        const float* xp = x + g * NPG * FIN;
        for (int e = t; e < NPG * FIN; e += 256) xg[e] = xp[e];
        for (int e = t; e < FIN * WID; e += 256) W1s[e] = W1[e];
        if (t < WID) b1s[t] = b1[t];
    }
    __syncthreads();

    const int ty = t >> 4, tx = t & 15;
    const int r0 = ty * 4, cj = tx * 8;   // own-local rows r0..r0+3, cols cj..cj+7

    // ---- A2_own = (A @ A)[i0+.., :] ----
    {
        float acc[4][8] = {};
        for (int k = 0; k < NPG; ++k) {
            float a[4];
            #pragma unroll
            for (int r = 0; r < 4; ++r) a[r] = Bs[(i0 + r0 + r) * 132 + k];
            float4 q0 = *(const float4*)&Bs[k * 132 + cj];
            float4 q1 = *(const float4*)&Bs[k * 132 + cj + 4];
            float bb[8] = {q0.x, q0.y, q0.z, q0.w, q1.x, q1.y, q1.z, q1.w};
            #pragma unroll
            for (int r = 0; r < 4; ++r)
                #pragma unroll
                for (int c = 0; c < 8; ++c)
                    acc[r][c] = fmaf(a[r], bb[c], acc[r][c]);
        }
        #pragma unroll
        for (int r = 0; r < 4; ++r) {
            *(float4*)&A2s[(r0 + r) * 132 + cj]     = make_float4(acc[r][0], acc[r][1], acc[r][2], acc[r][3]);
            *(float4*)&A2s[(r0 + r) * 132 + cj + 4] = make_float4(acc[r][4], acc[r][5], acc[r][6], acc[r][7]);
        }
    }
    __syncthreads();

    // ---- conv1: p2_own = A2_own @ x ; exchange p2 ; h1_full = leaky(p2_full @ W1 + b1) ----
    for (int e = t; e < 64 * FIN; e += 256) {    // 384 elems > 256 threads: MUST stride
        int i = e / FIN, d = e - (e / FIN) * FIN;
        float s = 0.f;
        for (int k = 0; k < NPG; ++k) s = fmaf(A2s[i * 132 + k], xg[k * FIN + d], s);
        p2f[(i0 + i) * 8 + d] = s;
        __hip_atomic_store(&Xp2[g * 1024 + (i0 + i) * 8 + d], s, __ATOMIC_RELAXED, AGENT);
    }
    gbar(cnt + g * 2 + 0, 2u);
    for (int e = t; e < 64 * FIN; e += 256) {
        int i = e / FIN, d = e - (e / FIN) * FIN;
        p2f[(i0p + i) * 8 + d] =
            __hip_atomic_load(&Xp2[g * 1024 + (i0p + i) * 8 + d], __ATOMIC_RELAXED, AGENT);
    }
    __syncthreads();
    for (int e = t; e < NPG * WID; e += 256) {   // h1_full over A (dead)
        int i = e >> 7, o = e & 127;
        float s = b1s[o];
        #pragma unroll
        for (int d = 0; d < FIN; ++d) s = fmaf(p2f[i * 8 + d], W1s[d * WID + o], s);
        Bs[i * 132 + o] = leaky(s);
    }
    __syncthreads();
    if (half == 0 && t < WID) {                  // pool h1 -> Zp[g][0:256]
        float sm = 0.f, mx = -BIG;
        for (int i = 0; i < NPG; ++i) { float v = Bs[i * 132 + t]; sm += v; mx = fmaxf(mx, v); }
        Zp[g * D2 + t]       = sm * (1.f / NPG);
        Zp[g * D2 + WID + t] = mx;
    }

    // ---- conv2: P_own = A2_own @ h1_full ; h2_own = leaky(P @ W2 + b2) ; exchange h2 ----
    {
        float acc[4][8] = {};
        for (int k = 0; k < NPG; ++k) {
            float a[4];
            #pragma unroll
            for (int r = 0; r < 4; ++r) a[r] = A2s[(r0 + r) * 132 + k];
            float4 q0 = *(const float4*)&Bs[k * 132 + cj];
            float4 q1 = *(const float4*)&Bs[k * 132 + cj + 4];
            float bb[8] = {q0.x, q0.y, q0.z, q0.w, q1.x, q1.y, q1.z, q1.w};
            #pragma unroll
            for (int r = 0; r < 4; ++r)
                #pragma unroll
                for (int c = 0; c < 8; ++c)
                    acc[r][c] = fmaf(a[r], bb[c], acc[r][c]);
        }
        #pragma unroll
        for (int r = 0; r < 4; ++r) {
            *(float4*)&Ps[(r0 + r) * 132 + cj]     = make_float4(acc[r][0], acc[r][1], acc[r][2], acc[r][3]);
            *(float4*)&Ps[(r0 + r) * 132 + cj + 4] = make_float4(acc[r][4], acc[r][5], acc[r][6], acc[r][7]);
        }
        __syncthreads();
        float o2[4][8] = {};
        const float* W2 = Wc;
        for (int d = 0; d < NPG; ++d) {
            float a[4];
            #pragma unroll
            for (int r = 0; r < 4; ++r) a[r] = Ps[(r0 + r) * 132 + d];
            float4 w0 = *(const float4*)&W2[d * WID + cj];
            float4 w1 = *(const float4*)&W2[d * WID + cj + 4];
            float bb[8] = {w0.x, w0.y, w0.z, w0.w, w1.x, w1.y, w1.z, w1.w};
            #pragma unroll
            for (int r = 0; r < 4; ++r)
                #pragma unroll
                for (int c = 0; c < 8; ++c)
                    o2[r][c] = fmaf(a[r], bb[c], o2[r][c]);
        }
        #pragma unroll
        for (int r = 0; r < 4; ++r)
            #pragma unroll
            for (int c = 0; c < 8; ++c)
                Bs[(i0 + r0 + r) * 132 + cj + c] = leaky(o2[r][c] + bc[cj + c]);
    }
    __syncthreads();
    for (int e = t; e < 64 * WID; e += 256) {    // own half -> global (coalesced agent)
        int i = i0 + (e >> 7), o = e & 127;
        __hip_atomic_store(&Xh2[(size_t)g * 16384 + i * WID + o], Bs[i * 132 + o],
                           __ATOMIC_RELAXED, AGENT);
    }
    gbar(cnt + g * 2 + 1, 2u);
    for (int e = t; e < 64 * WID; e += 256) {    // partner half <- global
        int i = i0p + (e >> 7), o = e & 127;
        Bs[i * 132 + o] =
            __hip_atomic_load(&Xh2[(size_t)g * 16384 + i * WID + o], __ATOMIC_RELAXED, AGENT);
    }
    __syncthreads();
    if (half == 0 && t < WID) {                  // pool h2 -> Zp[g][256:512]
        float sm = 0.f, mx = -BIG;
        for (int i = 0; i < NPG; ++i) { float v = Bs[i * 132 + t]; sm += v; mx = fmaxf(mx, v); }
        Zp[g * D2 + 256 + t]       = sm * (1.f / NPG);
        Zp[g * D2 + 256 + WID + t] = mx;
    }

    // ---- conv3: P_own = A2_own @ h2_full ; h3_own = leaky(P @ W3 + b3) ; partial pool ----
    {
        float acc[4][8] = {};
        for (int k = 0; k < NPG; ++k) {
            float a[4];
            #pragma unroll
            for (int r = 0; r < 4; ++r) a[r] = A2s[(r0 + r) * 132 + k];
            float4 q0 = *(const float4*)&Bs[k * 132 + cj];
            float4 q1 = *(const float4*)&Bs[k * 132 + cj + 4];
            float bb[8] = {q0.x, q0.y, q0.z, q0.w, q1.x, q1.y, q1.z, q1.w};
            #pragma unroll
            for (int r = 0; r < 4; ++r)
                #pragma unroll
                for (int c = 0; c < 8; ++c)
                    acc[r][c] = fmaf(a[r], bb[c], acc[r][c]);
        }
        __syncthreads();   // conv2's Ps readers all done
        #pragma unroll
        for (int r = 0; r < 4; ++r) {
            *(float4*)&Ps[(r0 + r) * 132 + cj]     = make_float4(acc[r][0], acc[r][1], acc[r][2], acc[r][3]);
            *(float4*)&Ps[(r0 + r) * 132 + cj + 4] = make_float4(acc[r][4], acc[r][5], acc[r][6], acc[r][7]);
        }
        __syncthreads();
        float o3[4][8] = {};
        const float* W3 = Wc + WID * WID;
        const float* b3 = bc + WID;
        for (int d = 0; d < NPG; ++d) {
            float a[4];
            #pragma unroll
            for (int r = 0; r < 4; ++r) a[r] = Ps[(r0 + r) * 132 + d];
            float4 w0 = *(const float4*)&W3[d * WID + cj];
            float4 w1 = *(const float4*)&W3[d * WID + cj + 4];
            float bb[8] = {w0.x, w0.y, w0.z, w0.w, w1.x, w1.y, w1.z, w1.w};
            #pragma unroll
            for (int r = 0; r < 4; ++r)
                #pragma unroll
                for (int c = 0; c < 8; ++c)
                    o3[r][c] = fmaf(a[r], bb[c], o3[r][c]);
        }
        __syncthreads();   // all Ps reads done -> overwrite with h3_own
        #pragma unroll
        for (int r = 0; r < 4; ++r)
            #pragma unroll
            for (int c = 0; c < 8; ++c)
                Ps[(r0 + r) * 132 + cj + c] = leaky(o3[r][c] + b3[cj + c]);
    }
    __syncthreads();
    if (t < WID) {                               // partial pool of own 64 rows of h3
        float sm = 0.f, mx = -BIG;
        for (int i = 0; i < 64; ++i) { float v = Ps[i * 132 + t]; sm += v; mx = fmaxf(mx, v); }
        Zp3[(size_t)(g * 2 + half) * 256 + t]       = sm;
        Zp3[(size_t)(g * 2 + half) * 256 + 128 + t] = mx;
    }
}

// ---------------- K3: tail: BN + 5 MLP layers + head. grid 48, block 256 ----------------
__device__ __forceinline__ float bn_val(const float* Zp, const float* Zp3, int c, int r)
{
    if (c < 512) return Zp[r * D2 + c];
    int o = c - 512;
    if (o < 128)
        return (Zp3[(size_t)(r * 2) * 256 + o] + Zp3[(size_t)(r * 2 + 1) * 256 + o]) * (1.f / NPG);
    o -= 128;
    return fmaxf(Zp3[(size_t)(r * 2) * 256 + 128 + o], Zp3[(size_t)(r * 2 + 1) * 256 + 128 + o]);
}

__global__ __launch_bounds__(256, 1) void k_tail(
    const float* __restrict__ Zp, const float* __restrict__ Zp3,
    const float* __restrict__ bng, const float* __restrict__ bnb,
    const float* __restrict__ linW, const float* __restrict__ linb,
    const float* __restrict__ outW, const float* __restrict__ outb,
    float* __restrict__ ZT0, float* __restrict__ ZT1,
    float* __restrict__ out, unsigned* __restrict__ cnt)
{
    const int b = blockIdx.x;        // 48 blocks x 16 cols
    const int t = threadIdx.x;
    const int c0 = b * 16;
    __shared__ float Wp[D2 * 16];    // 49 KB: W panel (also BN scratch)
    __shared__ float zc[2 * 64 * 68];// 34 KB: z chunks, double-buffered

    // ---- BN + transpose -> ZT0 ----
    {
        int sub = t >> 4, rq = t & 15;
        int c = c0 + sub;
        float s = 0.f, s2 = 0.f;
        #pragma unroll
        for (int rr = 0; rr < 4; ++rr) {
            float v = bn_val(Zp, Zp3, c, rq * 4 + rr);
            s += v; s2 = fmaf(v, v, s2);
        }
        Wp[sub * 16 + rq] = s;
        Wp[256 + sub * 16 + rq] = s2;
        __syncthreads();
        if (t < 16) {
            float ss = 0.f, qq = 0.f;
            #pragma unroll
            for (int q = 0; q < 16; ++q) { ss += Wp[t * 16 + q]; qq += Wp[256 + t * 16 + q]; }
            float m   = ss * (1.f / NG);
            float var = qq * (1.f / NG) - m * m;
            Wp[512 + t] = m;
            Wp[528 + t] = rsqrtf(var + BNEPS) * bng[c0 + t];
            Wp[544 + t] = bnb[c0 + t];
        }
        __syncthreads();
        float m = Wp[512 + sub], sc = Wp[528 + sub], bt = Wp[544 + sub];
        #pragma unroll
        for (int rr = 0; rr < 4; ++rr) {
            int r = rq * 4 + rr;
            float v = bn_val(Zp, Zp3, c, r);
            __hip_atomic_store(&ZT0[c * NG + r], (v - m) * sc + bt, __ATOMIC_RELAXED, AGENT);
        }
    }
    gbar(cnt + 128, 48u);

    // ---- 5 MLP layers ----
    const int w = t >> 6, r = t & 63;     // wave -> 4 cols, lane -> row
    for (int l = 0; l < 5; ++l) {
        const float* zin  = (l & 1) ? ZT1 : ZT0;
        float*       zout = (l & 1) ? ZT0 : ZT1;
        const float* Wl = linW + (size_t)l * D2 * D2;
        __syncthreads();                  // Wp free (prev layer compute done at barrier)
        for (int e4 = t; e4 < 3072; e4 += 256) {
            int k = e4 >> 2, cp = e4 & 3;
            *(float4*)&Wp[k * 16 + cp * 4] = *(const float4*)&Wl[(size_t)k * D2 + c0 + cp * 4];
        }
        float pf[16];
        #pragma unroll
        for (int i = 0; i < 16; ++i) {    // prologue: chunk 0
            int e = t + i * 256, rr = e & 63, kk = e >> 6;
            pf[i] = __hip_atomic_load(&zin[kk * NG + rr], __ATOMIC_RELAXED, AGENT);
        }
        #pragma unroll
        for (int i = 0; i < 16; ++i) {
            int e = t + i * 256, rr = e & 63, kk = e >> 6;
            zc[rr * 68 + kk] = pf[i];
        }
        __syncthreads();
        float acc[4] = {0.f, 0.f, 0.f, 0.f};
        for (int kb = 0; kb < 12; ++kb) {
            const float* zcur = &zc[(kb & 1) * (64 * 68)];
            if (kb < 11) {
                #pragma unroll
                for (int i = 0; i < 16; ++i) {
                    int e = t + i * 256, rr = e & 63, kk = e >> 6;
                    pf[i] = __hip_atomic_load(&zin[((kb + 1) * 64 + kk) * NG + rr],
                                              __ATOMIC_RELAXED, AGENT);
                }
            }
            #pragma unroll
            for (int k4 = 0; k4 < 16; ++k4) {
                float4 z4 = *(const float4*)&zcur[r * 68 + k4 * 4];
                const float* wp = &Wp[(kb * 64 + k4 * 4) * 16 + w * 4];
                float4 w0 = *(const float4*)&wp[0];
                float4 w1 = *(const float4*)&wp[16];
                float4 w2 = *(const float4*)&wp[32];
                float4 w3 = *(const float4*)&wp[48];
                acc[0] = fmaf(z4.x, w0.x, acc[0]); acc[1] = fmaf(z4.x, w0.y, acc[1]);
                acc[2] = fmaf(z4.x, w0.z, acc[2]); acc[3] = fmaf(z4.x, w0.w, acc[3]);
                acc[0] = fmaf(z4.y, w1.x, acc[0]); acc[1] = fmaf(z4.y, w1.y, acc[1]);
                acc[2] = fmaf(z4.y, w1.z, acc[2]); acc[3] = fmaf(z4.y, w1.w, acc[3]);
                acc[0] = fmaf(z4.z, w2.x, acc[0]); acc[1] = fmaf(z4.z, w2.y, acc[1]);
                acc[2] = fmaf(z4.z, w2.z, acc[2]); acc[3] = fmaf(z4.z, w2.w, acc[3]);
                acc[0] = fmaf(z4.w, w3.x, acc[0]); acc[1] = fmaf(z4.w, w3.y, acc[1]);
                acc[2] = fmaf(z4.w, w3.z, acc[2]); acc[3] = fmaf(z4.w, w3.w, acc[3]);
            }
            if (kb < 11) {
                float* znxt = &zc[((kb + 1) & 1) * (64 * 68)];
                #pragma unroll
                for (int i = 0; i < 16; ++i) {
                    int e = t + i * 256, rr = e & 63, kk = e >> 6;
                    znxt[rr * 68 + kk] = pf[i];
                }
            }
            __syncthreads();
        }
        #pragma unroll
        for (int cc = 0; cc < 4; ++cc) {
            int c = c0 + w * 4 + cc;
            __hip_atomic_store(&zout[c * NG + r], leaky(acc[cc] + linb[l * D2 + c]),
                               __ATOMIC_RELAXED, AGENT);
        }
        gbar(cnt + 128 + 1 + l, 48u);
    }

    // ---- head (block 0) ----
    if (b == 0) {
        for (int e = t; e < D2; e += 256) Wp[e] = outW[e];
        __syncthreads();
        int kq = t >> 6, rr = t & 63;
        float s = 0.f;
        #pragma unroll 16
        for (int k = kq * 192; k < kq * 192 + 192; ++k)
            s = fmaf(__hip_atomic_load(&ZT1[k * NG + rr], __ATOMIC_RELAXED, AGENT), Wp[k], s);
        zc[kq * 64 + rr] = s;
        __syncthreads();
        if (t < 64)
            out[t] = zc[t] + zc[64 + t] + zc[128 + t] + zc[192 + t] + outb[0];
    }
}

extern "C" void kernel_launch(void* const* d_in, const int* in_sizes, int n_in,
                              void* d_out, int out_size, void* d_ws, size_t ws_size,
                              hipStream_t stream)
{
    (void)in_sizes; (void)n_in; (void)out_size; (void)ws_size;
    const float* x       = (const float*)d_in[0];
    // d_in[1] = batch: fixed structure (i/128), unused
    const float* conv1_W = (const float*)d_in[2];
    const float* conv1_b = (const float*)d_in[3];
    const float* convs_W = (const float*)d_in[4];
    const float* convs_b = (const float*)d_in[5];
    const float* bn_g    = (const float*)d_in[6];
    const float* bn_b    = (const float*)d_in[7];
    const float* lin_W   = (const float*)d_in[8];
    const float* lin_b   = (const float*)d_in[9];
    const float* out_W   = (const float*)d_in[10];
    const float* out_b   = (const float*)d_in[11];

    float* f = (float*)d_ws;
    float* A   = f;                      // 1M floats
    float* Xh2 = f + (1 << 20);          // 1M
    float* Xp2 = f + (2 << 20);          // 65536
    float* Zp  = Xp2 + 65536;            // 49152
    float* Zp3 = Zp + NG * D2;           // 32768
    float* ZT0 = Zp3 + 32768;            // 49152
    float* ZT1 = ZT0 + NG * D2;          // 49152
    unsigned* cnt = (unsigned*)(f + (4 << 20));   // 16 MB offset; 1 KB of counters
    float* outp = (float*)d_out;

    hipMemsetAsync(cnt, 0, 1024, stream);
    k_knn  <<<dim3(512), dim3(256), 0, stream>>>(x, A);
    k_graph<<<dim3(128), dim3(256), 0, stream>>>(A, x, conv1_W, conv1_b, convs_W, convs_b,
                                                 Xp2, Xh2, Zp, Zp3, cnt);
    k_tail <<<dim3(48),  dim3(256), 0, stream>>>(Zp, Zp3, bn_g, bn_b, lin_W, lin_b,
                                                 out_W, out_b, ZT0, ZT1, outp, cnt);
}